// Round 2
// 927.477 us; speedup vs baseline: 1.0836x; 1.0836x over previous
//
#include <hip/hip_runtime.h>

#define DEFAULT_SCORE -10000.0f

// Layout: one 64-lane wave handles 16 rows; 4 lanes per row, 16B vector/lane.
//
// Key insight: cond = (self < max over 63 neighbour scores) is equivalent to
// ANY(neigh > self), and checking 15 random neighbours already resolves a row
// with P = 15/16. Two exact stages:
//   Stage 1: cols 0..15  -> ONE 64B nidx line/row, 16 gathers, ballot vote.
//            ~94% of rows finish here (cond=true proven).
//   Stage 2: cols 16..63 -> 192B + 48 gathers, exec-masked to ~6% of rows.
// This cuts score-gather L2 line-requests ~3.4x (64 -> ~19 per row) and nidx
// HBM fetch ~3x (256B -> ~80B per row); both were the measured bottleneck
// (23% HBM, 15% VALU => L2 gather request throughput bound).
//
// No shuffle reductions: ballot + per-4-lane-group bit test replaces the max.
// Streaming traffic (nidx, dist, outputs) is non-temporal so the 4 MB score
// table stays resident in each XCD's L2 for the gathers.
// NOTE: __builtin_nontemporal_* requires NATIVE vector types (ext_vector),
// not HIP's int4/float4 classes — that was last round's compile failure.
// Harness decodes d_out as float32 -> nidx_out written as float-encoded ints.

typedef int   iv4 __attribute__((ext_vector_type(4)));
typedef float fv4 __attribute__((ext_vector_type(4)));

constexpr int WAVE_ROWS = 16;  // 16 rows/wave, 4 lanes/row

__global__ __launch_bounds__(256) void dgb_kernel(
    const float* __restrict__ dist,
    const int*   __restrict__ nidx,
    const float* __restrict__ score,
    float*       __restrict__ dist_out,
    float*       __restrict__ nidx_out,
    int V) {
  const int lane = threadIdx.x & 63;
  const int wave = blockIdx.x * (blockDim.x >> 6) + (threadIdx.x >> 6);
  const int k    = lane & 3;              // lane within 4-lane row group
  const int row  = wave * WAVE_ROWS + (lane >> 2);
  const bool valid = row < V;
  const size_t rowbase = (size_t)row * 64;
  const int grp = lane & 60;              // ballot bit offset of my row group

  // ---- Stage 1: columns 0..15 (exactly one cache line of nidx per row) ----
  iv4 idx1 = (iv4)(-1);
  float self = 0.0f;
  if (valid) {
    idx1 = __builtin_nontemporal_load(
        reinterpret_cast<const iv4*>(nidx + rowbase) + k);
    self = score[row];  // sequential, L2-hot
  }
  float g0 = (idx1.x >= 0) ? score[idx1.x] : DEFAULT_SCORE;
  float g1 = (idx1.y >= 0) ? score[idx1.y] : DEFAULT_SCORE;
  float g2 = (idx1.z >= 0) ? score[idx1.z] : DEFAULT_SCORE;
  float g3 = (idx1.w >= 0) ? score[idx1.w] : DEFAULT_SCORE;
  if (k == 0) g0 = DEFAULT_SCORE;  // column 0 is the self index, not a neighbour
  const bool p1 = fmaxf(fmaxf(g0, g1), fmaxf(g2, g3)) > self;
  const unsigned long long b1 = __ballot(p1);
  const bool resolved = ((b1 >> grp) & 0xFull) != 0;  // cond proven true

  // ---- Stage 2: columns 16..63, only for still-unresolved rows (~6%) ----
  float m2 = DEFAULT_SCORE;
  if (valid && !resolved) {
#pragma unroll
    for (int j = 0; j < 3; ++j) {
      const iv4 id = __builtin_nontemporal_load(
          reinterpret_cast<const iv4*>(nidx + rowbase + 16 + j * 16) + k);
      const float h0 = (id.x >= 0) ? score[id.x] : DEFAULT_SCORE;
      const float h1 = (id.y >= 0) ? score[id.y] : DEFAULT_SCORE;
      const float h2 = (id.z >= 0) ? score[id.z] : DEFAULT_SCORE;
      const float h3 = (id.w >= 0) ? score[id.w] : DEFAULT_SCORE;
      m2 = fmaxf(m2, fmaxf(fmaxf(h0, h1), fmaxf(h2, h3)));
    }
  }
  const unsigned long long b2 = __ballot(m2 > self);
  const bool cond = resolved || (((b2 >> grp) & 0xFull) != 0);

  if (!valid) return;

  // ---- Output: lane k writes column chunks 16j+4k..+3 (16B each) ----
#pragma unroll
  for (int j = 0; j < 4; ++j) {
    const size_t off = rowbase + (size_t)j * 16 + (size_t)k * 4;
    fv4 d4, n4;
    if (cond) {
      d4 = (fv4)(0.0f);
      const float nx = (j == 0 && k == 0) ? (float)idx1.x : -1.0f;
      n4 = (fv4){nx, -1.0f, -1.0f, -1.0f};
    } else {
      // ~1.6% of rows: exact passthrough (reload is L2-cheap and rare)
      d4 = __builtin_nontemporal_load(
          reinterpret_cast<const fv4*>(dist + off));
      iv4 id;
      if (j == 0) id = idx1;
      else
        id = __builtin_nontemporal_load(
            reinterpret_cast<const iv4*>(nidx + off));
      n4 = (fv4){(float)id.x, (float)id.y, (float)id.z, (float)id.w};
    }
    __builtin_nontemporal_store(d4, reinterpret_cast<fv4*>(dist_out + off));
    __builtin_nontemporal_store(n4, reinterpret_cast<fv4*>(nidx_out + off));
  }
}

extern "C" void kernel_launch(void* const* d_in, const int* in_sizes, int n_in,
                              void* d_out, int out_size, void* d_ws, size_t ws_size,
                              hipStream_t stream) {
  const float* dist  = (const float*)d_in[0];  // [V, 64] f32
  const int*   nidx  = (const int*)d_in[1];    // [V, 64] i32
  const float* score = (const float*)d_in[2];  // [V, 1]  f32

  const int V = in_sizes[2];

  float* dist_out = (float*)d_out;                    // V*64 floats
  float* nidx_out = (float*)d_out + (size_t)V * 64;   // V*64 float-encoded ints

  const int rows_per_block = (256 / 64) * WAVE_ROWS;  // 4 waves x 16 rows = 64
  const int grid = (V + rows_per_block - 1) / rows_per_block;

  dgb_kernel<<<grid, 256, 0, stream>>>(dist, nidx, score, dist_out, nidx_out, V);
}

// Round 3
// 786.067 us; speedup vs baseline: 1.2785x; 1.1799x over previous
//
#include <hip/hip_runtime.h>

#define DEFAULT_SCORE -10000.0f

// Two phases inside one kernel; one 64-lane wave owns 64 consecutive rows.
//
// Phase 1 (decision, LANE-PER-ROW): cond(row) = any(score[nbr] > score[row]).
//   Check neighbours in chunks of 4 with per-chunk early exit (cols 0..15 are
//   one cache line -> chunks 1..3 are L1-hot), then 16-wide chunks for the
//   ~6% of rows still alive. Expected score-gathers/row ~6 instead of the
//   previous 16 (L2 request count was a measured co-bottleneck: 23% HBM,
//   15% VALU, both pipes idle => request/latency bound).
//   No ballots/votes: cond is naturally per-lane. Self index needs no load:
//   nidx[v,0] == v by convention.
//
// Phase 2 (output, WAVE-COOPERATIVE): the wave's 64 rows are contiguous, so
//   each store instruction covers 1 KB of contiguous memory (4 rows x 256 B:
//   lane = 16*sub + c writes row sub, floats 4c..4c+3). Dropped rows (98.4%)
//   write zeros / {row,-1...}; passthrough rows (1.6%) reload dist/nidx via
//   exec-masked NT loads (L2-cheap, rare).
//
// All streaming traffic is non-temporal so the 4 MB score[] table stays
// resident in each XCD's L2 for the gathers.
// __builtin_nontemporal_* requires native ext_vector types, not HIP int4.
// Harness decodes d_out as float32 -> nidx_out written as float-encoded ints.

typedef int   iv4 __attribute__((ext_vector_type(4)));
typedef float fv4 __attribute__((ext_vector_type(4)));

__global__ __launch_bounds__(256) void dgb_kernel(
    const float* __restrict__ dist,
    const int*   __restrict__ nidx,
    const float* __restrict__ score,
    float*       __restrict__ dist_out,
    float*       __restrict__ nidx_out,
    int V) {
  const int lane = threadIdx.x & 63;
  const int wave = blockIdx.x * (blockDim.x >> 6) + (threadIdx.x >> 6);
  const int wrow0 = wave << 6;  // first of this wave's 64 rows

  // ---------------- Phase 1: decision (lane-per-row) ----------------
  const int row = wrow0 + lane;
  const bool valid = row < V;
  const size_t rb = (size_t)row << 6;
  const iv4* rowp = reinterpret_cast<const iv4*>(nidx + rb);

  float self = 0.0f;
  if (valid) self = score[row];  // sequential, L2-hot
  bool done = !valid;            // done == "cond proven true" (or row invalid)

  // chunk 0: cols 0..3 (col 0 is the self index -> 3 neighbours)
  if (!done) {
    const iv4 a = __builtin_nontemporal_load(rowp);
    const float g1 = (a.y >= 0) ? score[a.y] : DEFAULT_SCORE;
    const float g2 = (a.z >= 0) ? score[a.z] : DEFAULT_SCORE;
    const float g3 = (a.w >= 0) ? score[a.w] : DEFAULT_SCORE;
    if (fmaxf(fmaxf(g1, g2), g3) > self) done = true;
  }
  // chunks 1..3: cols 4..15, 4 neighbours each, early-exit between chunks
#pragma unroll
  for (int c = 1; c < 4; ++c) {
    if (__any(!done)) {
      if (!done) {
        const iv4 a = __builtin_nontemporal_load(rowp + c);
        const float g0 = (a.x >= 0) ? score[a.x] : DEFAULT_SCORE;
        const float g1 = (a.y >= 0) ? score[a.y] : DEFAULT_SCORE;
        const float g2 = (a.z >= 0) ? score[a.z] : DEFAULT_SCORE;
        const float g3 = (a.w >= 0) ? score[a.w] : DEFAULT_SCORE;
        if (fmaxf(fmaxf(g0, g1), fmaxf(g2, g3)) > self) done = true;
      }
    }
  }
  // big chunks: cols 16..63 in three 16-wide gulps for the ~6% survivors
#pragma unroll
  for (int c = 1; c < 4; ++c) {
    if (__any(!done)) {
      if (!done) {
        const iv4* p = rowp + 4 * c;
        const iv4 a0 = __builtin_nontemporal_load(p);
        const iv4 a1 = __builtin_nontemporal_load(p + 1);
        const iv4 a2 = __builtin_nontemporal_load(p + 2);
        const iv4 a3 = __builtin_nontemporal_load(p + 3);
        float m = DEFAULT_SCORE;
        m = fmaxf(m, (a0.x >= 0) ? score[a0.x] : DEFAULT_SCORE);
        m = fmaxf(m, (a0.y >= 0) ? score[a0.y] : DEFAULT_SCORE);
        m = fmaxf(m, (a0.z >= 0) ? score[a0.z] : DEFAULT_SCORE);
        m = fmaxf(m, (a0.w >= 0) ? score[a0.w] : DEFAULT_SCORE);
        m = fmaxf(m, (a1.x >= 0) ? score[a1.x] : DEFAULT_SCORE);
        m = fmaxf(m, (a1.y >= 0) ? score[a1.y] : DEFAULT_SCORE);
        m = fmaxf(m, (a1.z >= 0) ? score[a1.z] : DEFAULT_SCORE);
        m = fmaxf(m, (a1.w >= 0) ? score[a1.w] : DEFAULT_SCORE);
        m = fmaxf(m, (a2.x >= 0) ? score[a2.x] : DEFAULT_SCORE);
        m = fmaxf(m, (a2.y >= 0) ? score[a2.y] : DEFAULT_SCORE);
        m = fmaxf(m, (a2.z >= 0) ? score[a2.z] : DEFAULT_SCORE);
        m = fmaxf(m, (a2.w >= 0) ? score[a2.w] : DEFAULT_SCORE);
        m = fmaxf(m, (a3.x >= 0) ? score[a3.x] : DEFAULT_SCORE);
        m = fmaxf(m, (a3.y >= 0) ? score[a3.y] : DEFAULT_SCORE);
        m = fmaxf(m, (a3.z >= 0) ? score[a3.z] : DEFAULT_SCORE);
        m = fmaxf(m, (a3.w >= 0) ? score[a3.w] : DEFAULT_SCORE);
        if (m > self) done = true;
      }
    }
  }
  // For rows that never found a larger neighbour, done stays false == cond
  // false (passthrough). done == cond for all valid rows at this point.
  const unsigned long long cbits = __ballot(done && valid);

  // ---------------- Phase 2: output (wave-cooperative) ----------------
  // Store instr s covers rows 4s..4s+3 fully: 1 KB contiguous per instr.
  const int sub  = lane >> 4;        // row offset within the 4-row group
  const int col0 = (lane & 15) << 2; // starting float column
#pragma unroll 4
  for (int s = 0; s < 16; ++s) {
    const int r = (s << 2) + sub;    // row index within wave, 0..63
    const int orow = wrow0 + r;
    if (wrow0 + (s << 2) >= V) break;  // wave-uniform tail cut
    const bool c = (cbits >> r) & 1ull;
    const size_t off = ((size_t)orow << 6) + col0;

    fv4 d4 = (fv4)(0.0f);
    fv4 n4 = {(col0 == 0) ? (float)orow : -1.0f, -1.0f, -1.0f, -1.0f};
    if (orow < V && !c) {  // ~1.6% of rows: exact passthrough
      d4 = __builtin_nontemporal_load(
          reinterpret_cast<const fv4*>(dist + off));
      const iv4 id = __builtin_nontemporal_load(
          reinterpret_cast<const iv4*>(nidx + off));
      n4 = (fv4){(float)id.x, (float)id.y, (float)id.z, (float)id.w};
    }
    if (orow < V) {
      __builtin_nontemporal_store(d4, reinterpret_cast<fv4*>(dist_out + off));
      __builtin_nontemporal_store(n4, reinterpret_cast<fv4*>(nidx_out + off));
    }
  }
}

extern "C" void kernel_launch(void* const* d_in, const int* in_sizes, int n_in,
                              void* d_out, int out_size, void* d_ws, size_t ws_size,
                              hipStream_t stream) {
  const float* dist  = (const float*)d_in[0];  // [V, 64] f32
  const int*   nidx  = (const int*)d_in[1];    // [V, 64] i32
  const float* score = (const float*)d_in[2];  // [V, 1]  f32

  const int V = in_sizes[2];

  float* dist_out = (float*)d_out;                    // V*64 floats
  float* nidx_out = (float*)d_out + (size_t)V * 64;   // V*64 float-encoded ints

  const int rows_per_block = 4 * 64;  // 4 waves x 64 rows
  const int grid = (V + rows_per_block - 1) / rows_per_block;

  dgb_kernel<<<grid, 256, 0, stream>>>(dist, nidx, score, dist_out, nidx_out, V);
}